// Round 2
// baseline (429.075 us; speedup 1.0000x reference)
//
#include <hip/hip_runtime.h>
#include <math.h>

// Problem constants (from reference setup_inputs)
#define BB 8
#define CC 19
#define HH 544
#define WW 960

// Tile geometry: 32x64 outputs per 256-thread block.
// 960/64 = 15, 544/32 = 17 -> exact tiling.
#define TH 32
#define TW 64
#define HALO 3              // 2 (blur) + 1 (maxpool)
#define HT (TH + 6)         // 38 staged heat rows
#define WT (TW + 6)         // 70 staged heat cols
#define BR (TH + 2)         // 34 blurred rows (output +- 1 for maxpool)
#define BC (TW + 2)         // 66 blurred cols

__device__ __forceinline__ int reflect_h(int i) {
    i = (i < 0) ? -i : i;
    return (i >= HH) ? (2 * HH - 2 - i) : i;
}
__device__ __forceinline__ int reflect_w(int i) {
    i = (i < 0) ? -i : i;
    return (i >= WW) ? (2 * WW - 2 - i) : i;
}

__global__ __launch_bounds__(256)
void skel_fused_kernel(const float* __restrict__ heat,
                       const float* __restrict__ k1d,
                       float* __restrict__ out)
{
    // CRITICAL: the harness validates against a numpy fp32 reference, and the
    // NMS step (blurred == maxes) flips whole peaks on a 1-ulp blur difference.
    // numpy never fuses mul+add, so forbid FP contraction and accumulate the
    // 5-tap sums left-to-right with separate mul/add, exactly like
    // acc = k0*x0; acc += k1*x1; ... in numpy.
    #pragma clang fp contract(off)

    __shared__ float sh[HT][WT];    // staged heat tile (+3 halo)
    __shared__ float stmp[BR][WT];  // vertically-blurred
    __shared__ float sbl[BR][BC];   // fully blurred (-inf outside image)

    const int wt = blockIdx.x;      // 0..14
    const int ht = blockIdx.y;      // 0..16
    const int pl = blockIdx.z;      // 0..151 (b*C + c)
    const int h0 = ht * TH;
    const int w0 = wt * TW;
    const int tid = threadIdx.x;

    const float k0 = k1d[0], k1 = k1d[1], k2 = k1d[2], k3 = k1d[3], k4 = k1d[4];

    const float* __restrict__ plane = heat + (size_t)pl * (HH * WW);

    // ---- stage heat tile with reflect padding ----
    for (int idx = tid; idx < HT * WT; idx += 256) {
        const int r = idx / WT, c = idx % WT;
        const int gr = reflect_h(h0 - HALO + r);
        const int gc = reflect_w(w0 - HALO + c);
        sh[r][c] = plane[gr * WW + gc];
    }
    __syncthreads();

    // ---- vertical 5-tap pass (reference order: H-conv first), no FMA,
    //      left-to-right accumulation ----
    for (int idx = tid; idx < BR * WT; idx += 256) {
        const int tr = idx / WT, tc = idx % WT;
        float v = sh[tr][tc] * k0;
        v = v + sh[tr + 1][tc] * k1;
        v = v + sh[tr + 2][tc] * k2;
        v = v + sh[tr + 3][tc] * k3;
        v = v + sh[tr + 4][tc] * k4;
        stmp[tr][tc] = v;
    }
    __syncthreads();

    // ---- horizontal 5-tap pass -> blurred; -inf outside the image so the
    // 3x3 max-pool's -inf padding falls out naturally ----
    for (int idx = tid; idx < BR * BC; idx += 256) {
        const int br = idx / BC, bc = idx % BC;
        const int gbr = h0 - 1 + br;
        const int gbc = w0 - 1 + bc;
        float v;
        if (gbr >= 0 && gbr < HH && gbc >= 0 && gbc < WW) {
            v = stmp[br][bc] * k0;
            v = v + stmp[br][bc + 1] * k1;
            v = v + stmp[br][bc + 2] * k2;
            v = v + stmp[br][bc + 3] * k3;
            v = v + stmp[br][bc + 4] * k4;
        } else {
            v = -INFINITY;
        }
        sbl[br][bc] = v;
    }
    __syncthreads();

    // ---- 3x3 max-pool + NMS + threshold; write 3 outputs ----
    const size_t N = (size_t)BB * CC * HH * WW;
    float* __restrict__ out_peaks = out;
    float* __restrict__ out_maxes = out + N;
    float* __restrict__ out_blur  = out + 2 * N;

    for (int idx = tid; idx < TH * TW; idx += 256) {
        const int orow = idx / TW, ocol = idx % TW;
        const int br = orow + 1, bc = ocol + 1;
        const float b = sbl[br][bc];
        float m = b;
        m = fmaxf(m, sbl[br - 1][bc - 1]);
        m = fmaxf(m, sbl[br - 1][bc]);
        m = fmaxf(m, sbl[br - 1][bc + 1]);
        m = fmaxf(m, sbl[br][bc - 1]);
        m = fmaxf(m, sbl[br][bc + 1]);
        m = fmaxf(m, sbl[br + 1][bc - 1]);
        m = fmaxf(m, sbl[br + 1][bc]);
        m = fmaxf(m, sbl[br + 1][bc + 1]);
        // numpy compares fp32 promoted to fp64 against python 0.1 (fp64):
        // b == 0.1f (fp64 0.10000000149 > 0.1) must be KEPT -> use >=
        const float p = (b == m && b >= 0.1f) ? b : 0.0f;
        const size_t o = (size_t)pl * (HH * WW) + (size_t)(h0 + orow) * WW + (w0 + ocol);
        out_peaks[o] = p;
        out_maxes[o] = m;
        out_blur[o]  = b;
    }
}

extern "C" void kernel_launch(void* const* d_in, const int* in_sizes, int n_in,
                              void* d_out, int out_size, void* d_ws, size_t ws_size,
                              hipStream_t stream) {
    const float* heat = (const float*)d_in[0];
    const float* k1d  = (const float*)d_in[1];
    float* out = (float*)d_out;

    dim3 grid(WW / TW, HH / TH, BB * CC);   // 15 x 17 x 152
    dim3 block(256);
    skel_fused_kernel<<<grid, block, 0, stream>>>(heat, k1d, out);
}

// Round 3
// 404.338 us; speedup vs baseline: 1.0612x; 1.0612x over previous
//
#include <hip/hip_runtime.h>
#include <math.h>

// Problem constants (from reference setup_inputs)
#define BB 8
#define CC 19
#define HH 544
#define WW 960

// Tile geometry: 32x64 outputs per 256-thread block. 960/64=15, 544/32=17.
#define TH 32
#define TW 64
#define HALO 3              // 2 (blur) + 1 (maxpool)
#define HT (TH + 6)         // 38 staged heat rows
#define WT 72               // staged row stride (TW+6=70 padded to mult of 4 for b128)
#define BR (TH + 2)         // 34 blurred rows (output +-1 for maxpool)
#define BCP 68              // blurred padded width (TW+2=66 padded to 68)

// bit-exactness: numpy reference never fuses mul+add; forbid contraction
// everywhere and accumulate 5-tap sums left-to-right.
#pragma clang fp contract(off)

__device__ __forceinline__ int reflect_h(int i) {
    i = (i < 0) ? -i : i;
    return (i >= HH) ? (2 * HH - 2 - i) : i;
}
__device__ __forceinline__ int reflect_w(int i) {
    i = (i < 0) ? -i : i;
    return (i >= WW) ? (2 * WW - 2 - i) : i;
}

__device__ __forceinline__ float conv5(float s0, float s1, float s2, float s3,
                                       float s4, float k0, float k1, float k2,
                                       float k3, float k4) {
    #pragma clang fp contract(off)
    float v = s0 * k0;
    v = v + s1 * k1;
    v = v + s2 * k2;
    v = v + s3 * k3;
    v = v + s4 * k4;
    return v;
}

__global__ __launch_bounds__(256)
void skel_fused_kernel(const float* __restrict__ heat,
                       const float* __restrict__ k1d,
                       float* __restrict__ out)
{
    #pragma clang fp contract(off)

    __shared__ float sh[HT][WT];    // 38*72*4 = 10944 B
    __shared__ float stmp[BR][WT];  // 34*72*4 =  9792 B
    __shared__ float sbl[BR][BCP];  // 34*68*4 =  9248 B   (total ~29.3 KB)

    const int wt = blockIdx.x;      // 0..14
    const int ht = blockIdx.y;      // 0..16
    const int pl = blockIdx.z;      // 0..151
    const int h0 = ht * TH;
    const int w0 = wt * TW;
    const int tid = threadIdx.x;

    const float k0 = k1d[0], k1 = k1d[1], k2 = k1d[2], k3 = k1d[3], k4 = k1d[4];

    const float* __restrict__ plane = heat + (size_t)pl * (HH * WW);

    // ---- stage heat tile (scalar; reflect padding) ----
    for (int idx = tid; idx < HT * WT; idx += 256) {
        const int r = idx / WT, c = idx % WT;
        const int gr = reflect_h(h0 - HALO + r);
        const int gc = reflect_w(w0 - HALO + c);
        sh[r][c] = plane[gr * WW + gc];
    }
    __syncthreads();

    // ---- vertical 5-tap pass, float4 per thread ----
    for (int idx = tid; idx < BR * (WT / 4); idx += 256) {
        const int tr = idx / (WT / 4), q = idx % (WT / 4);
        const float4 a0 = *(const float4*)&sh[tr + 0][q * 4];
        const float4 a1 = *(const float4*)&sh[tr + 1][q * 4];
        const float4 a2 = *(const float4*)&sh[tr + 2][q * 4];
        const float4 a3 = *(const float4*)&sh[tr + 3][q * 4];
        const float4 a4 = *(const float4*)&sh[tr + 4][q * 4];
        float4 v;
        v.x = conv5(a0.x, a1.x, a2.x, a3.x, a4.x, k0, k1, k2, k3, k4);
        v.y = conv5(a0.y, a1.y, a2.y, a3.y, a4.y, k0, k1, k2, k3, k4);
        v.z = conv5(a0.z, a1.z, a2.z, a3.z, a4.z, k0, k1, k2, k3, k4);
        v.w = conv5(a0.w, a1.w, a2.w, a3.w, a4.w, k0, k1, k2, k3, k4);
        *(float4*)&stmp[tr][q * 4] = v;
    }
    __syncthreads();

    // ---- horizontal 5-tap pass -> blurred (-inf outside image) ----
    for (int idx = tid; idx < BR * (BCP / 4); idx += 256) {
        const int br = idx / (BCP / 4), q = idx % (BCP / 4);
        const int bc0 = q * 4;
        const float4 a = *(const float4*)&stmp[br][bc0];
        const float4 b4 = *(const float4*)&stmp[br][bc0 + 4];
        // s0..s7 = cols bc0..bc0+7
        float4 v;
        v.x = conv5(a.x, a.y, a.z, a.w, b4.x, k0, k1, k2, k3, k4);
        v.y = conv5(a.y, a.z, a.w, b4.x, b4.y, k0, k1, k2, k3, k4);
        v.z = conv5(a.z, a.w, b4.x, b4.y, b4.z, k0, k1, k2, k3, k4);
        v.w = conv5(a.w, b4.x, b4.y, b4.z, b4.w, k0, k1, k2, k3, k4);
        const int gbr = h0 - 1 + br;
        const bool rowok = (gbr >= 0) && (gbr < HH);
        const int gbc = w0 - 1 + bc0;
        v.x = (rowok && gbc + 0 >= 0 && gbc + 0 < WW) ? v.x : -INFINITY;
        v.y = (rowok && gbc + 1 >= 0 && gbc + 1 < WW) ? v.y : -INFINITY;
        v.z = (rowok && gbc + 2 >= 0 && gbc + 2 < WW) ? v.z : -INFINITY;
        v.w = (rowok && gbc + 3 >= 0 && gbc + 3 < WW) ? v.w : -INFINITY;
        *(float4*)&sbl[br][bc0] = v;
    }
    __syncthreads();

    // ---- 3x3 max-pool + NMS + threshold; float4 stores ----
    const size_t N = (size_t)BB * CC * HH * WW;
    float* __restrict__ out_peaks = out;
    float* __restrict__ out_maxes = out + N;
    float* __restrict__ out_blur  = out + 2 * N;

    for (int idx = tid; idx < TH * (TW / 4); idx += 256) {
        const int orow = idx / (TW / 4), qc = idx % (TW / 4);
        const int oc0 = qc * 4;
        // sbl rows orow..orow+2; cols oc0..oc0+5 (two aligned f4 reads/row)
        const float4 t0a = *(const float4*)&sbl[orow + 0][oc0];
        const float4 t0b = *(const float4*)&sbl[orow + 0][oc0 + 4];
        const float4 t1a = *(const float4*)&sbl[orow + 1][oc0];
        const float4 t1b = *(const float4*)&sbl[orow + 1][oc0 + 4];
        const float4 t2a = *(const float4*)&sbl[orow + 2][oc0];
        const float4 t2b = *(const float4*)&sbl[orow + 2][oc0 + 4];

        // per-row 3-wide window max
        float4 r0, r1, r2;
        r0.x = fmaxf(fmaxf(t0a.x, t0a.y), t0a.z);
        r0.y = fmaxf(fmaxf(t0a.y, t0a.z), t0a.w);
        r0.z = fmaxf(fmaxf(t0a.z, t0a.w), t0b.x);
        r0.w = fmaxf(fmaxf(t0a.w, t0b.x), t0b.y);
        r1.x = fmaxf(fmaxf(t1a.x, t1a.y), t1a.z);
        r1.y = fmaxf(fmaxf(t1a.y, t1a.z), t1a.w);
        r1.z = fmaxf(fmaxf(t1a.z, t1a.w), t1b.x);
        r1.w = fmaxf(fmaxf(t1a.w, t1b.x), t1b.y);
        r2.x = fmaxf(fmaxf(t2a.x, t2a.y), t2a.z);
        r2.y = fmaxf(fmaxf(t2a.y, t2a.z), t2a.w);
        r2.z = fmaxf(fmaxf(t2a.z, t2a.w), t2b.x);
        r2.w = fmaxf(fmaxf(t2a.w, t2b.x), t2b.y);

        float4 m;
        m.x = fmaxf(fmaxf(r0.x, r1.x), r2.x);
        m.y = fmaxf(fmaxf(r0.y, r1.y), r2.y);
        m.z = fmaxf(fmaxf(r0.z, r1.z), r2.z);
        m.w = fmaxf(fmaxf(r0.w, r1.w), r2.w);

        // blurred value = middle row, cols oc0+1..oc0+4
        float4 b;
        b.x = t1a.y; b.y = t1a.z; b.z = t1a.w; b.w = t1b.x;

        // numpy compares fp32 promoted to fp64 vs python 0.1: b==0.1f kept -> >=
        float4 p;
        p.x = (b.x == m.x && b.x >= 0.1f) ? b.x : 0.0f;
        p.y = (b.y == m.y && b.y >= 0.1f) ? b.y : 0.0f;
        p.z = (b.z == m.z && b.z >= 0.1f) ? b.z : 0.0f;
        p.w = (b.w == m.w && b.w >= 0.1f) ? b.w : 0.0f;

        const size_t o = (size_t)pl * (HH * WW) + (size_t)(h0 + orow) * WW + (w0 + oc0);
        *(float4*)&out_peaks[o] = p;
        *(float4*)&out_maxes[o] = m;
        *(float4*)&out_blur[o]  = b;
    }
}

extern "C" void kernel_launch(void* const* d_in, const int* in_sizes, int n_in,
                              void* d_out, int out_size, void* d_ws, size_t ws_size,
                              hipStream_t stream) {
    const float* heat = (const float*)d_in[0];
    const float* k1d  = (const float*)d_in[1];
    float* out = (float*)d_out;

    dim3 grid(WW / TW, HH / TH, BB * CC);   // 15 x 17 x 152
    dim3 block(256);
    skel_fused_kernel<<<grid, block, 0, stream>>>(heat, k1d, out);
}

// Round 4
// 247.971 us; speedup vs baseline: 1.7303x; 1.6306x over previous
//
#include <hip/hip_runtime.h>
#include <math.h>

// Problem constants (from reference setup_inputs)
#define BB 8
#define CC 19
#define HH 544
#define WW 960

// Tile: 32x64 outputs per 256-thread block. 960/64=15, 544/32=17.
#define TH 32
#define TW 64
#define HT 38               // staged heat rows  (TH+6)
#define WT 76               // staged row stride: cols w0-4 .. w0+71 (f4-aligned)
#define BR 34               // blurred rows (TH+2)
#define BCP 68              // blurred row stride (TW+2 padded to 68)

#define SH_FLOATS  (HT * WT)            // 2888
#define STMP_FLOATS (BR * WT)           // 2584
// sbl (34*68=2312 floats) aliases sh (dead after vertical pass)
// total LDS = (2888+2584)*4 = 21888 B -> 7 blocks/CU (was 5)

typedef float f4 __attribute__((ext_vector_type(4)));

// bit-exactness vs numpy fp32 reference: never fuse mul+add, accumulate
// the 5-tap sum left-to-right (NMS blurred==maxes flips whole peaks on 1 ulp).
#pragma clang fp contract(off)

__device__ __forceinline__ int reflect_h(int i) {
    i = (i < 0) ? -i : i;
    return (i >= HH) ? (2 * HH - 2 - i) : i;
}
__device__ __forceinline__ int reflect_w(int i) {
    i = (i < 0) ? -i : i;
    return (i >= WW) ? (2 * WW - 2 - i) : i;
}

__device__ __forceinline__ float conv5(float s0, float s1, float s2, float s3,
                                       float s4, float k0, float k1, float k2,
                                       float k3, float k4) {
    #pragma clang fp contract(off)
    float v = s0 * k0;
    v = v + s1 * k1;
    v = v + s2 * k2;
    v = v + s3 * k3;
    v = v + s4 * k4;
    return v;
}

__global__ __launch_bounds__(256)
void skel_fused_kernel(const float* __restrict__ heat,
                       const float* __restrict__ k1d,
                       float* __restrict__ out)
{
    #pragma clang fp contract(off)

    __shared__ float smem[SH_FLOATS + STMP_FLOATS];
    float* const sh   = smem;                 // [HT][WT]
    float* const stmp = smem + SH_FLOATS;     // [BR][WT]
    float* const sbl  = smem;                 // [BR][BCP], aliases sh

    const int wt = blockIdx.x;      // 0..14
    const int ht = blockIdx.y;      // 0..16
    const int pl = blockIdx.z;      // 0..151
    const int h0 = ht * TH;
    const int w0 = wt * TW;
    const int tid = threadIdx.x;

    const float k0 = k1d[0], k1 = k1d[1], k2 = k1d[2], k3 = k1d[3], k4 = k1d[4];

    const float* __restrict__ plane = heat + (size_t)pl * (HH * WW);

    // interior <=> staged window rows [h0-3, h0+35) and cols [w0-4, w0+72)
    // are fully inside the image, and all maxpool windows are in-image.
    const bool interior = (wt >= 1) & (wt <= 13) & (ht >= 1) & (ht <= 15);

    // ---- stage heat tile: sh[r][c] = heat[h0-3+r][w0-4+c] ----
    if (interior) {
        // float4 loads, no reflect: 38 rows x 19 f4-groups = 722
        for (int idx = tid; idx < HT * (WT / 4); idx += 256) {
            const int r = idx / (WT / 4), q = idx % (WT / 4);
            const int gr = h0 - 3 + r;
            const int gc = w0 - 4 + q * 4;
            *(f4*)&sh[r * WT + q * 4] = *(const f4*)&plane[gr * WW + gc];
        }
    } else {
        for (int idx = tid; idx < HT * WT; idx += 256) {
            const int r = idx / WT, c = idx % WT;
            const int gr = reflect_h(h0 - 3 + r);
            const int gc = reflect_w(w0 - 4 + c);
            sh[r * WT + c] = plane[gr * WW + gc];
        }
    }
    __syncthreads();

    // ---- vertical 5-tap pass: stmp[tr][c] over full 76-wide rows ----
    for (int idx = tid; idx < BR * (WT / 4); idx += 256) {
        const int tr = idx / (WT / 4), q = idx % (WT / 4);
        const f4 a0 = *(const f4*)&sh[(tr + 0) * WT + q * 4];
        const f4 a1 = *(const f4*)&sh[(tr + 1) * WT + q * 4];
        const f4 a2 = *(const f4*)&sh[(tr + 2) * WT + q * 4];
        const f4 a3 = *(const f4*)&sh[(tr + 3) * WT + q * 4];
        const f4 a4 = *(const f4*)&sh[(tr + 4) * WT + q * 4];
        f4 v;
        v.x = conv5(a0.x, a1.x, a2.x, a3.x, a4.x, k0, k1, k2, k3, k4);
        v.y = conv5(a0.y, a1.y, a2.y, a3.y, a4.y, k0, k1, k2, k3, k4);
        v.z = conv5(a0.z, a1.z, a2.z, a3.z, a4.z, k0, k1, k2, k3, k4);
        v.w = conv5(a0.w, a1.w, a2.w, a3.w, a4.w, k0, k1, k2, k3, k4);
        *(f4*)&stmp[tr * WT + q * 4] = v;
    }
    __syncthreads();

    // ---- horizontal 5-tap -> sbl (aliases sh; safe after the sync).
    // sbl col bc = global blurred col (w0 + bc - 1); its 5-tap window is
    // stmp sCols bc+1 .. bc+5  (sCol = gc - (w0-4)).
    for (int idx = tid; idx < BR * (BCP / 4); idx += 256) {
        const int br = idx / (BCP / 4), q = idx % (BCP / 4);
        const int bc0 = q * 4;
        const f4 A = *(const f4*)&stmp[br * WT + bc0];
        const f4 B = *(const f4*)&stmp[br * WT + bc0 + 4];
        const f4 C = *(const f4*)&stmp[br * WT + bc0 + 8];
        f4 v;
        v.x = conv5(A.y, A.z, A.w, B.x, B.y, k0, k1, k2, k3, k4);
        v.y = conv5(A.z, A.w, B.x, B.y, B.z, k0, k1, k2, k3, k4);
        v.z = conv5(A.w, B.x, B.y, B.z, B.w, k0, k1, k2, k3, k4);
        v.w = conv5(B.x, B.y, B.z, B.w, C.x, k0, k1, k2, k3, k4);
        if (!interior) {
            const int gbr = h0 - 1 + br;
            const bool rowok = (gbr >= 0) & (gbr < HH);
            const int gbc = w0 - 1 + bc0;
            v.x = (rowok & (gbc + 0 >= 0) & (gbc + 0 < WW)) ? v.x : -INFINITY;
            v.y = (rowok & (gbc + 1 >= 0) & (gbc + 1 < WW)) ? v.y : -INFINITY;
            v.z = (rowok & (gbc + 2 >= 0) & (gbc + 2 < WW)) ? v.z : -INFINITY;
            v.w = (rowok & (gbc + 3 >= 0) & (gbc + 3 < WW)) ? v.w : -INFINITY;
        }
        *(f4*)&sbl[br * BCP + bc0] = v;
    }
    __syncthreads();

    // ---- 3x3 max-pool + NMS + threshold; non-temporal f4 stores ----
    const size_t N = (size_t)BB * CC * HH * WW;
    float* __restrict__ out_peaks = out;
    float* __restrict__ out_maxes = out + N;
    float* __restrict__ out_blur  = out + 2 * N;

    for (int idx = tid; idx < TH * (TW / 4); idx += 256) {
        const int orow = idx >> 4, qc = idx & 15;
        const int oc0 = qc * 4;
        const f4 t0a = *(const f4*)&sbl[(orow + 0) * BCP + oc0];
        const f4 t0b = *(const f4*)&sbl[(orow + 0) * BCP + oc0 + 4];
        const f4 t1a = *(const f4*)&sbl[(orow + 1) * BCP + oc0];
        const f4 t1b = *(const f4*)&sbl[(orow + 1) * BCP + oc0 + 4];
        const f4 t2a = *(const f4*)&sbl[(orow + 2) * BCP + oc0];
        const f4 t2b = *(const f4*)&sbl[(orow + 2) * BCP + oc0 + 4];

        f4 r0, r1, r2;
        r0.x = fmaxf(fmaxf(t0a.x, t0a.y), t0a.z);
        r0.y = fmaxf(fmaxf(t0a.y, t0a.z), t0a.w);
        r0.z = fmaxf(fmaxf(t0a.z, t0a.w), t0b.x);
        r0.w = fmaxf(fmaxf(t0a.w, t0b.x), t0b.y);
        r1.x = fmaxf(fmaxf(t1a.x, t1a.y), t1a.z);
        r1.y = fmaxf(fmaxf(t1a.y, t1a.z), t1a.w);
        r1.z = fmaxf(fmaxf(t1a.z, t1a.w), t1b.x);
        r1.w = fmaxf(fmaxf(t1a.w, t1b.x), t1b.y);
        r2.x = fmaxf(fmaxf(t2a.x, t2a.y), t2a.z);
        r2.y = fmaxf(fmaxf(t2a.y, t2a.z), t2a.w);
        r2.z = fmaxf(fmaxf(t2a.z, t2a.w), t2b.x);
        r2.w = fmaxf(fmaxf(t2a.w, t2b.x), t2b.y);

        f4 m;
        m.x = fmaxf(fmaxf(r0.x, r1.x), r2.x);
        m.y = fmaxf(fmaxf(r0.y, r1.y), r2.y);
        m.z = fmaxf(fmaxf(r0.z, r1.z), r2.z);
        m.w = fmaxf(fmaxf(r0.w, r1.w), r2.w);

        f4 b;
        b.x = t1a.y; b.y = t1a.z; b.z = t1a.w; b.w = t1b.x;

        // numpy compares fp32 promoted to fp64 vs python 0.1: b==0.1f kept -> >=
        f4 p;
        p.x = (b.x == m.x && b.x >= 0.1f) ? b.x : 0.0f;
        p.y = (b.y == m.y && b.y >= 0.1f) ? b.y : 0.0f;
        p.z = (b.z == m.z && b.z >= 0.1f) ? b.z : 0.0f;
        p.w = (b.w == m.w && b.w >= 0.1f) ? b.w : 0.0f;

        const size_t o = (size_t)pl * (HH * WW) + (size_t)(h0 + orow) * WW + (w0 + oc0);
        __builtin_nontemporal_store(p, (f4*)&out_peaks[o]);
        __builtin_nontemporal_store(m, (f4*)&out_maxes[o]);
        __builtin_nontemporal_store(b, (f4*)&out_blur[o]);
    }
}

extern "C" void kernel_launch(void* const* d_in, const int* in_sizes, int n_in,
                              void* d_out, int out_size, void* d_ws, size_t ws_size,
                              hipStream_t stream) {
    const float* heat = (const float*)d_in[0];
    const float* k1d  = (const float*)d_in[1];
    float* out = (float*)d_out;

    dim3 grid(WW / TW, HH / TH, BB * CC);   // 15 x 17 x 152
    dim3 block(256);
    skel_fused_kernel<<<grid, block, 0, stream>>>(heat, k1d, out);
}

// Round 5
// 227.463 us; speedup vs baseline: 1.8863x; 1.0902x over previous
//
#include <hip/hip_runtime.h>
#include <math.h>

// Problem constants (from reference setup_inputs)
#define BB 8
#define CC 19
#define HH 544
#define WW 960

// Tile: 64x64 outputs per 512-thread block. 960/64=15; H: 8 full + 1 partial(32).
#define TW 64
#define WT 72               // staged row stride: cols w0-4 .. w0+67 (f4-aligned)
#define BCP 68              // blurred row stride (TW+2 padded to 68)
#define HT_MAX 70           // 64+6 staged rows (full tile)
#define BR_MAX 66           // 64+2 blurred rows

#define SH_FLOATS   (HT_MAX * WT)       // 5040
#define STMP_FLOATS (BR_MAX * WT + 4)   // 4756 (+4: q=16 C-read spills 4 floats)
// sbl (66*68=4488 floats) aliases sh (dead after vertical pass)
// total LDS = (5040+4756)*4 = 39184 B -> 4 blocks/CU x 8 waves = 32 waves/CU (max)

typedef float f4 __attribute__((ext_vector_type(4)));

// bit-exactness vs numpy fp32 reference: never fuse mul+add, accumulate
// the 5-tap sum left-to-right (NMS blurred==maxes flips whole peaks on 1 ulp).
#pragma clang fp contract(off)

__device__ __forceinline__ int reflect_h(int i) {
    i = (i < 0) ? -i : i;
    return (i >= HH) ? (2 * HH - 2 - i) : i;
}
__device__ __forceinline__ int reflect_w(int i) {
    i = (i < 0) ? -i : i;
    return (i >= WW) ? (2 * WW - 2 - i) : i;
}

__device__ __forceinline__ float conv5(float s0, float s1, float s2, float s3,
                                       float s4, float k0, float k1, float k2,
                                       float k3, float k4) {
    #pragma clang fp contract(off)
    float v = s0 * k0;
    v = v + s1 * k1;
    v = v + s2 * k2;
    v = v + s3 * k3;
    v = v + s4 * k4;
    return v;
}

__global__ __launch_bounds__(512)
void skel_fused_kernel(const float* __restrict__ heat,
                       const float* __restrict__ k1d,
                       float* __restrict__ out)
{
    #pragma clang fp contract(off)

    __shared__ float smem[SH_FLOATS + STMP_FLOATS];
    float* const sh   = smem;                 // [ht_rows][WT]
    float* const stmp = smem + SH_FLOATS;     // [br_rows][WT]
    float* const sbl  = smem;                 // [br_rows][BCP], aliases sh

    const int wt = blockIdx.x;      // 0..14
    const int ht = blockIdx.y;      // 0..8
    const int pl = blockIdx.z;      // 0..151
    const int h0 = ht * 64;
    const int w0 = wt * TW;
    const int tid = threadIdx.x;

    const int th_rows = (h0 + 64 <= HH) ? 64 : (HH - h0);  // 64, or 32 at ht=8
    const int ht_rows = th_rows + 6;
    const int br_rows = th_rows + 2;

    const float k0 = k1d[0], k1 = k1d[1], k2 = k1d[2], k3 = k1d[3], k4 = k1d[4];

    const float* __restrict__ plane = heat + (size_t)pl * (HH * WW);

    // interior <=> staged rows [h0-3, h0+67) and cols [w0-4, w0+68) in-image
    const bool interior = (wt >= 1) & (wt <= 13) & (ht >= 1) & (ht <= 7);

    // ---- stage heat tile: sh[r][c] = heat[h0-3+r][w0-4+c] ----
    if (interior) {
        for (int idx = tid; idx < ht_rows * (WT / 4); idx += 512) {
            const int r = idx / (WT / 4), q = idx % (WT / 4);
            const int gr = h0 - 3 + r;
            const int gc = w0 - 4 + q * 4;
            *(f4*)&sh[r * WT + q * 4] = *(const f4*)&plane[gr * WW + gc];
        }
    } else {
        for (int idx = tid; idx < ht_rows * WT; idx += 512) {
            const int r = idx / WT, c = idx % WT;
            const int gr = reflect_h(h0 - 3 + r);
            const int gc = reflect_w(w0 - 4 + c);
            sh[r * WT + c] = plane[gr * WW + gc];
        }
    }
    __syncthreads();

    // ---- vertical 5-tap pass: stmp[tr][*] from sh rows tr..tr+4 ----
    for (int idx = tid; idx < br_rows * (WT / 4); idx += 512) {
        const int tr = idx / (WT / 4), q = idx % (WT / 4);
        const f4 a0 = *(const f4*)&sh[(tr + 0) * WT + q * 4];
        const f4 a1 = *(const f4*)&sh[(tr + 1) * WT + q * 4];
        const f4 a2 = *(const f4*)&sh[(tr + 2) * WT + q * 4];
        const f4 a3 = *(const f4*)&sh[(tr + 3) * WT + q * 4];
        const f4 a4 = *(const f4*)&sh[(tr + 4) * WT + q * 4];
        f4 v;
        v.x = conv5(a0.x, a1.x, a2.x, a3.x, a4.x, k0, k1, k2, k3, k4);
        v.y = conv5(a0.y, a1.y, a2.y, a3.y, a4.y, k0, k1, k2, k3, k4);
        v.z = conv5(a0.z, a1.z, a2.z, a3.z, a4.z, k0, k1, k2, k3, k4);
        v.w = conv5(a0.w, a1.w, a2.w, a3.w, a4.w, k0, k1, k2, k3, k4);
        *(f4*)&stmp[tr * WT + q * 4] = v;
    }
    __syncthreads();

    // ---- horizontal 5-tap -> sbl (aliases sh; safe after the sync).
    // sbl col bc = blurred col (w0-1+bc); window = stmp scols bc+1 .. bc+5.
    // q=16: C spills into next stmp row / +4 pad; feeds only pad cols 66,67.
    for (int idx = tid; idx < br_rows * (BCP / 4); idx += 512) {
        const int br = idx / (BCP / 4), q = idx % (BCP / 4);
        const int bc0 = q * 4;
        const f4 A = *(const f4*)&stmp[br * WT + bc0];
        const f4 B = *(const f4*)&stmp[br * WT + bc0 + 4];
        const f4 C = *(const f4*)&stmp[br * WT + bc0 + 8];
        f4 v;
        v.x = conv5(A.y, A.z, A.w, B.x, B.y, k0, k1, k2, k3, k4);
        v.y = conv5(A.z, A.w, B.x, B.y, B.z, k0, k1, k2, k3, k4);
        v.z = conv5(A.w, B.x, B.y, B.z, B.w, k0, k1, k2, k3, k4);
        v.w = conv5(B.x, B.y, B.z, B.w, C.x, k0, k1, k2, k3, k4);
        if (!interior) {
            const int gbr = h0 - 1 + br;
            const bool rowok = (gbr >= 0) & (gbr < HH);
            const int gbc = w0 - 1 + bc0;
            v.x = (rowok & (gbc + 0 >= 0) & (gbc + 0 < WW)) ? v.x : -INFINITY;
            v.y = (rowok & (gbc + 1 >= 0) & (gbc + 1 < WW)) ? v.y : -INFINITY;
            v.z = (rowok & (gbc + 2 >= 0) & (gbc + 2 < WW)) ? v.z : -INFINITY;
            v.w = (rowok & (gbc + 3 >= 0) & (gbc + 3 < WW)) ? v.w : -INFINITY;
        }
        *(f4*)&sbl[br * BCP + bc0] = v;
    }
    __syncthreads();

    // ---- 3x3 max-pool + NMS + threshold; non-temporal f4 stores ----
    const size_t N = (size_t)BB * CC * HH * WW;
    float* __restrict__ out_peaks = out;
    float* __restrict__ out_maxes = out + N;
    float* __restrict__ out_blur  = out + 2 * N;

    for (int idx = tid; idx < th_rows * (TW / 4); idx += 512) {
        const int orow = idx >> 4, qc = idx & 15;
        const int oc0 = qc * 4;
        const f4 t0a = *(const f4*)&sbl[(orow + 0) * BCP + oc0];
        const f4 t0b = *(const f4*)&sbl[(orow + 0) * BCP + oc0 + 4];
        const f4 t1a = *(const f4*)&sbl[(orow + 1) * BCP + oc0];
        const f4 t1b = *(const f4*)&sbl[(orow + 1) * BCP + oc0 + 4];
        const f4 t2a = *(const f4*)&sbl[(orow + 2) * BCP + oc0];
        const f4 t2b = *(const f4*)&sbl[(orow + 2) * BCP + oc0 + 4];

        f4 r0, r1, r2;
        r0.x = fmaxf(fmaxf(t0a.x, t0a.y), t0a.z);
        r0.y = fmaxf(fmaxf(t0a.y, t0a.z), t0a.w);
        r0.z = fmaxf(fmaxf(t0a.z, t0a.w), t0b.x);
        r0.w = fmaxf(fmaxf(t0a.w, t0b.x), t0b.y);
        r1.x = fmaxf(fmaxf(t1a.x, t1a.y), t1a.z);
        r1.y = fmaxf(fmaxf(t1a.y, t1a.z), t1a.w);
        r1.z = fmaxf(fmaxf(t1a.z, t1a.w), t1b.x);
        r1.w = fmaxf(fmaxf(t1a.w, t1b.x), t1b.y);
        r2.x = fmaxf(fmaxf(t2a.x, t2a.y), t2a.z);
        r2.y = fmaxf(fmaxf(t2a.y, t2a.z), t2a.w);
        r2.z = fmaxf(fmaxf(t2a.z, t2a.w), t2b.x);
        r2.w = fmaxf(fmaxf(t2a.w, t2b.x), t2b.y);

        f4 m;
        m.x = fmaxf(fmaxf(r0.x, r1.x), r2.x);
        m.y = fmaxf(fmaxf(r0.y, r1.y), r2.y);
        m.z = fmaxf(fmaxf(r0.z, r1.z), r2.z);
        m.w = fmaxf(fmaxf(r0.w, r1.w), r2.w);

        f4 b;
        b.x = t1a.y; b.y = t1a.z; b.z = t1a.w; b.w = t1b.x;

        // numpy compares fp32 promoted to fp64 vs python 0.1: b==0.1f kept -> >=
        f4 p;
        p.x = (b.x == m.x && b.x >= 0.1f) ? b.x : 0.0f;
        p.y = (b.y == m.y && b.y >= 0.1f) ? b.y : 0.0f;
        p.z = (b.z == m.z && b.z >= 0.1f) ? b.z : 0.0f;
        p.w = (b.w == m.w && b.w >= 0.1f) ? b.w : 0.0f;

        const size_t o = (size_t)pl * (HH * WW) + (size_t)(h0 + orow) * WW + (w0 + oc0);
        __builtin_nontemporal_store(p, (f4*)&out_peaks[o]);
        __builtin_nontemporal_store(m, (f4*)&out_maxes[o]);
        __builtin_nontemporal_store(b, (f4*)&out_blur[o]);
    }
}

extern "C" void kernel_launch(void* const* d_in, const int* in_sizes, int n_in,
                              void* d_out, int out_size, void* d_ws, size_t ws_size,
                              hipStream_t stream) {
    const float* heat = (const float*)d_in[0];
    const float* k1d  = (const float*)d_in[1];
    float* out = (float*)d_out;

    dim3 grid(WW / TW, (HH + 63) / 64, BB * CC);   // 15 x 9 x 152
    dim3 block(512);
    skel_fused_kernel<<<grid, block, 0, stream>>>(heat, k1d, out);
}